// Round 1
// baseline (211.688 us; speedup 1.0000x reference)
//
#include <hip/hip_runtime.h>

#define NN 30000
#define NE 390000
#define HH 64
#define NGRAPH 64

// ---------- sortable float encoding (ascending order preserved in uint) ----------
__device__ __forceinline__ unsigned sortable_f32(float f) {
    unsigned u = __float_as_uint(f);
    return (u & 0x80000000u) ? ~u : (u | 0x80000000u);
}
__device__ __forceinline__ float unsortable_f32(unsigned s) {
    unsigned u = (s & 0x80000000u) ? (s & 0x7fffffffu) : ~s;
    return __uint_as_float(u);
}

// tabs layout (float offsets):
// TV=0 (32x64), TC1=2048 (16x64), TC2=3072 (16x64), TC3=4096 (4x64),
// TQ=4352, TK=6400, TEK=8448 (each 32x64), TA=10496 (32x32), TB=11520 (32x32)
#define T_V   0
#define T_C1  2048
#define T_C2  3072
#define T_C3  4096
#define T_Q   4352
#define T_K   6400
#define T_EK  8448
#define T_A   10496
#define T_B   11520

__global__ void k_tab1(const float* __restrict__ emb_sbv, const float* __restrict__ emb_sbr,
                       const float* __restrict__ emb_edge, const float* __restrict__ emb_static,
                       const float* __restrict__ Wq, const float* __restrict__ Wk,
                       const float* __restrict__ Wv, const float* __restrict__ Wek,
                       const float* __restrict__ Wc, float* __restrict__ tabs) {
    int idx = blockIdx.x * 256 + threadIdx.x;
    if (idx >= 10496) return;
    float acc = 0.f;
    if (idx < 2048) {              // TV = emb_sbv @ Wv.T
        int r = idx >> 6, h = idx & 63;
        for (int j = 0; j < 64; ++j) acc += emb_sbv[r*64+j] * Wv[h*64+j];
        tabs[T_V + idx] = acc;
    } else if (idx < 3072) {       // TC1 = emb_edge @ Wc[:,0:64].T
        int t = idx - 2048; int r = t >> 6, h = t & 63;
        for (int j = 0; j < 64; ++j) acc += emb_edge[r*64+j] * Wc[h*192+j];
        tabs[T_C1 + t] = acc;
    } else if (idx < 4096) {       // TC2 = emb_edge @ Wc[:,64:128].T
        int t = idx - 3072; int r = t >> 6, h = t & 63;
        for (int j = 0; j < 64; ++j) acc += emb_edge[r*64+j] * Wc[h*192+64+j];
        tabs[T_C2 + t] = acc;
    } else if (idx < 4352) {       // TC3 = emb_static @ Wc[:,128:192].T
        int t = idx - 4096; int r = t >> 6, h = t & 63;
        for (int j = 0; j < 64; ++j) acc += emb_static[r*64+j] * Wc[h*192+128+j];
        tabs[T_C3 + t] = acc;
    } else if (idx < 6400) {       // TQ
        int t = idx - 4352; int r = t >> 6, h = t & 63;
        for (int j = 0; j < 64; ++j) acc += emb_sbv[r*64+j] * Wq[h*64+j];
        tabs[T_Q + t] = acc;
    } else if (idx < 8448) {       // TK
        int t = idx - 6400; int r = t >> 6, h = t & 63;
        for (int j = 0; j < 64; ++j) acc += emb_sbv[r*64+j] * Wk[h*64+j];
        tabs[T_K + t] = acc;
    } else {                       // TEK = emb_sbr @ Wek.T
        int t = idx - 8448; int r = t >> 6, h = t & 63;
        for (int j = 0; j < 64; ++j) acc += emb_sbr[r*64+j] * Wek[h*64+j];
        tabs[T_EK + t] = acc;
    }
}

__global__ void k_tab2(float* __restrict__ tabs) {
    int idx = blockIdx.x * 256 + threadIdx.x;
    if (idx >= 2048) return;
    const float* TQ = tabs + T_Q;
    float acc = 0.f;
    if (idx < 1024) {              // A[r1][r0] = TQ[r1]·TK[r0] / 8
        int r1 = idx >> 5, r0 = idx & 31;
        const float* TK = tabs + T_K;
        for (int j = 0; j < 64; ++j) acc += TQ[r1*64+j] * TK[r0*64+j];
        tabs[T_A + idx] = acc * 0.125f;
    } else {                       // B[r1][rk] = TQ[r1]·TEK[rk] / 8
        int t = idx - 1024; int r1 = t >> 5, rk = t & 31;
        const float* TEK = tabs + T_EK;
        for (int j = 0; j < 64; ++j) acc += TQ[r1*64+j] * TEK[rk*64+j];
        tabs[T_B + t] = acc * 0.125f;
    }
}

// per-node even state + node selection atomicMin
__global__ void k_node1(const int4* __restrict__ node_states, const float* __restrict__ scalars,
                        const int* __restrict__ batch_vec, int* __restrict__ ns,
                        unsigned long long* __restrict__ nodeSel) {
    int i = blockIdx.x * 256 + threadIdx.x;
    if (i >= NN) return;
    int4 b = node_states[i];
    int st = 2 * (b.x + 2*b.y + 4*b.z + 8*b.w);
    ns[i] = st;
    int key = (st >> 1) * NGRAPH + batch_vec[i];
    unsigned long long pk = ((unsigned long long)sortable_f32(scalars[i]) << 32) | (unsigned)i;
    atomicMin(&nodeSel[key], pk);
}

__global__ void k_node2(const int* __restrict__ ns, const int* __restrict__ batch_vec,
                        const unsigned long long* __restrict__ nodeSel, int* __restrict__ row) {
    int i = blockIdx.x * 256 + threadIdx.x;
    if (i >= NN) return;
    int st = ns[i];
    int key = (st >> 1) * NGRAPH + batch_vec[i];
    unsigned win = (unsigned)(nodeSel[key] & 0xffffffffull);
    row[i] = st + (win == (unsigned)i ? 1 : 0);
}

// per-edge: static feature idx, edge-state idx, edge selection atomicMin
__global__ void k_edge1(const int4* __restrict__ edge_states, const float* __restrict__ scalars,
                        const int* __restrict__ ei0, const int* __restrict__ ei1,
                        const int* __restrict__ ns, unsigned char* __restrict__ esi,
                        unsigned long long* __restrict__ edgeSel) {
    int e = blockIdx.x * 256 + threadIdx.x;
    if (e >= NE) return;
    int4 b = edge_states[e];
    int es = b.x + 2*b.y + 4*b.z + 8*b.w;
    float sc = scalars[e];
    int s0 = ei0[e], s1 = ei1[e];
    float send = scalars[s0], recv = scalars[s1];
    int si = (sc < recv ? 1 : 0) + (send + sc < recv ? 2 : 0);
    esi[e] = (unsigned char)(es | (si << 4));
    int st = ns[s0];
    int key = (st >> 1) * NN + s1;
    unsigned long long pk = ((unsigned long long)sortable_f32(sc) << 32) | (unsigned)e;
    atomicMin(&edgeSel[key], pk);
}

// per-edge: alpha from A/B tables, running segment max, pack info
__global__ void k_edge2(const int* __restrict__ ei0, const int* __restrict__ ei1,
                        const int* __restrict__ ns, const int* __restrict__ row,
                        const unsigned long long* __restrict__ edgeSel,
                        const unsigned char* __restrict__ esi, const int* __restrict__ rev_idx,
                        const float* __restrict__ tabs, float* __restrict__ alphaArr,
                        unsigned* __restrict__ einfo, unsigned* __restrict__ mArr) {
    int e = blockIdx.x * 256 + threadIdx.x;
    if (e >= NE) return;
    int s0 = ei0[e], s1 = ei1[e];
    int st = ns[s0];
    int key = (st >> 1) * NN + s1;
    unsigned win = (unsigned)(edgeSel[key] & 0xffffffffull);
    int ekrow = st + (win == (unsigned)e ? 1 : 0);
    int r0 = row[s0], r1 = row[s1];
    float alpha = tabs[T_A + r1*32 + r0] + tabs[T_B + r1*32 + ekrow];
    alphaArr[e] = alpha;
    atomicMax(&mArr[s1], sortable_f32(alpha));
    unsigned inf = esi[e];
    unsigned infr = esi[rev_idx[e]];
    einfo[e] = (unsigned)r0 | ((inf & 15u) << 5) | ((infr & 15u) << 9) | ((inf >> 4) << 13);
}

// per-edge: exp and segment sum
__global__ void k_edge3(const int* __restrict__ ei1, const unsigned* __restrict__ mArr,
                        const int* __restrict__ step_ptr, float* __restrict__ alphaArr,
                        float* __restrict__ ssum) {
    int e = blockIdx.x * 256 + threadIdx.x;
    if (e >= NE) return;
    int step = step_ptr[0];
    float tau;
    if (step == -1) tau = 1.0f;
    else { float frac = fminf((float)step / 10000.f, 1.f); tau = 3.0f + (0.1f - 3.0f) * frac; }
    int s1 = ei1[e];
    float m = unsortable_f32(mArr[s1]);
    float ex = expf((alphaArr[e] - m) / tau);
    alphaArr[e] = ex;
    unsafeAtomicAdd(&ssum[s1], ex);
}

// node_out base = emb_sbv[row]
__global__ void k_node3(const int* __restrict__ row, const float* __restrict__ emb_sbv,
                        float* __restrict__ out_node) {
    int t = blockIdx.x * 256 + threadIdx.x;
    if (t >= NN * HH) return;
    int i = t >> 6, h = t & 63;
    out_node[t] = emb_sbv[row[i]*64 + h];
}

// final: wave-per-edge — message, edge_out write, node_out atomic accumulate
__global__ __launch_bounds__(256) void k_edge4(const int* __restrict__ ei1,
        const unsigned* __restrict__ einfo, const float* __restrict__ exArr,
        const float* __restrict__ ssum, const float* __restrict__ tabs,
        const float* __restrict__ emb_edge, float* __restrict__ out_node,
        float* __restrict__ out_edge) {
    __shared__ float lds[5376];
    int tid = threadIdx.x;
    for (int j = tid; j < 4352; j += 256) lds[j] = tabs[j];       // TV,TC1,TC2,TC3
    for (int j = tid; j < 1024; j += 256) lds[4352 + j] = emb_edge[j];
    __syncthreads();
    const float* TV  = lds;
    const float* TC1 = lds + 2048;
    const float* TC2 = lds + 3072;
    const float* TC3 = lds + 4096;
    const float* EE  = lds + 4352;
    int lane = tid & 63;
    int wv = (blockIdx.x * 256 + tid) >> 6;
    int nw = (gridDim.x * 256) >> 6;
    for (int e = wv; e < NE; e += nw) {
        unsigned info = einfo[e];
        int s1 = ei1[e];
        float p = exArr[e] / ssum[s1];
        int r0 = info & 31;
        int es  = (info >> 5) & 15;
        int esr = (info >> 9) & 15;
        int si  = (info >> 13) & 3;
        float msg = p * (TV[r0*64 + lane] + TC1[es*64 + lane] + TC2[esr*64 + lane] + TC3[si*64 + lane]);
        out_edge[(size_t)e * 64 + lane] = EE[es*64 + lane] + msg;
        unsafeAtomicAdd(&out_node[(size_t)s1 * 64 + lane], msg);
    }
}

extern "C" void kernel_launch(void* const* d_in, const int* in_sizes, int n_in,
                              void* d_out, int out_size, void* d_ws, size_t ws_size,
                              hipStream_t stream) {
    const int4*  node_states = (const int4*)d_in[0];
    const int4*  edge_states = (const int4*)d_in[1];
    const float* scalars     = (const float*)d_in[2];
    const int*   edge_index  = (const int*)d_in[3];
    const int*   batch_vec   = (const int*)d_in[4];
    const int*   rev_idx     = (const int*)d_in[5];
    const float* emb_edge    = (const float*)d_in[6];
    const float* emb_sbv     = (const float*)d_in[7];
    const float* emb_sbr     = (const float*)d_in[8];
    const float* emb_static  = (const float*)d_in[9];
    const float* Wq  = (const float*)d_in[10];
    const float* Wk  = (const float*)d_in[11];
    const float* Wv  = (const float*)d_in[12];
    const float* Wek = (const float*)d_in[13];
    const float* Wc  = (const float*)d_in[15];
    const int*   step = (const int*)d_in[16];

    const int* ei0 = edge_index;
    const int* ei1 = edge_index + NE;

    char* ws = (char*)d_ws;
    // workspace layout (byte offsets, all 16B aligned)
    unsigned long long* edgeSel = (unsigned long long*)(ws);            // 16*NN u64 = 3,840,000
    unsigned long long* nodeSel = (unsigned long long*)(ws + 3840000);  // 1024 u64  = 8,192
    unsigned* mArr   = (unsigned*)(ws + 3848192);                       // NN u32
    float*    ssum   = (float*)(ws + 3968192);                          // NN f32
    int*      ns     = (int*)(ws + 4088192);                            // NN
    int*      rowArr = (int*)(ws + 4208192);                            // NN
    unsigned char* esi = (unsigned char*)(ws + 4328192);                // NE
    float*    alphaArr = (float*)(ws + 4718192);                        // NE f32
    unsigned* einfo  = (unsigned*)(ws + 6278192);                       // NE u32
    float*    tabs   = (float*)(ws + 7838192);                          // 12544 f32

    float* out_node = (float*)d_out;
    float* out_edge = out_node + (size_t)NN * HH;

    // init: selection slots to max (0xFF), softmax max/sum to 0
    hipMemsetAsync(ws, 0xFF, 3848192, stream);
    hipMemsetAsync(ws + 3848192, 0, 240000, stream);

    hipLaunchKernelGGL(k_tab1, dim3(41), dim3(256), 0, stream,
                       emb_sbv, emb_sbr, emb_edge, emb_static, Wq, Wk, Wv, Wek, Wc, tabs);
    hipLaunchKernelGGL(k_tab2, dim3(8), dim3(256), 0, stream, tabs);

    int nb_node = (NN + 255) / 256;
    int nb_edge = (NE + 255) / 256;

    hipLaunchKernelGGL(k_node1, dim3(nb_node), dim3(256), 0, stream,
                       node_states, scalars, batch_vec, ns, nodeSel);
    hipLaunchKernelGGL(k_edge1, dim3(nb_edge), dim3(256), 0, stream,
                       edge_states, scalars, ei0, ei1, ns, esi, edgeSel);
    hipLaunchKernelGGL(k_node2, dim3(nb_node), dim3(256), 0, stream,
                       ns, batch_vec, nodeSel, rowArr);
    hipLaunchKernelGGL(k_edge2, dim3(nb_edge), dim3(256), 0, stream,
                       ei0, ei1, ns, rowArr, edgeSel, esi, rev_idx, tabs, alphaArr, einfo, mArr);
    hipLaunchKernelGGL(k_edge3, dim3(nb_edge), dim3(256), 0, stream,
                       ei1, mArr, step, alphaArr, ssum);
    hipLaunchKernelGGL(k_node3, dim3((NN * HH + 255) / 256), dim3(256), 0, stream,
                       rowArr, emb_sbv, out_node);
    hipLaunchKernelGGL(k_edge4, dim3(2048), dim3(256), 0, stream,
                       ei1, einfo, alphaArr, ssum, tabs, emb_edge, out_node, out_edge);
}